// Round 8
// baseline (305.628 us; speedup 1.0000x reference)
//
#include <hip/hip_runtime.h>
#include <hip/hip_bf16.h>

typedef __hip_bfloat16 bf16;
typedef __attribute__((ext_vector_type(8))) short short8;
typedef __attribute__((ext_vector_type(4))) float f32x4;
typedef __attribute__((ext_vector_type(4))) unsigned short us4;
typedef __attribute__((ext_vector_type(2))) unsigned short us2;

#define B_  16
#define C_  512
#define T_  1024
#define G_  32
#define CPG 16
#define E_  1024
#define NH  8
#define CH  64
#define CT  (C_ * T_)   // 524288 elements per batch (1 MiB as bf16)

__device__ __forceinline__ float b2f(bf16 v) { return __bfloat162float(v); }
// fast RNE f32->bf16 (finite inputs only)
__device__ __forceinline__ unsigned short fbits_fast(float v) {
  unsigned int u = __builtin_bit_cast(unsigned int, v);
  u += 0x7fff + ((u >> 16) & 1);
  return (unsigned short)(u >> 16);
}
__device__ __forceinline__ bf16 f2b_fast(float v) {
  unsigned short s = fbits_fast(v);
  return *reinterpret_cast<bf16*>(&s);
}
// packed f32x2 -> bf16x2 in ONE VALU op (RNE, matches fbits_fast on finites)
__device__ __forceinline__ unsigned int cvtpk(float lo, float hi) {
  unsigned int r;
  asm("v_cvt_pk_bf16_f32 %0, %1, %2" : "=v"(r) : "v"(lo), "v"(hi));
  return r;
}

// async global->LDS, 16B per lane; LDS dest must be wave-uniform base; data
// lands at base + lane*16.
__device__ __forceinline__ void gload16(const void* g, void* l) {
  __builtin_amdgcn_global_load_lds(
      (const __attribute__((address_space(1))) void*)g,
      (__attribute__((address_space(3))) void*)l, 16, 0, 0);
}

// ---------------------------------------------------------------------------
// K0: fused prep kernel (1024 thr): blockIdx partition
//   [0, nconv)         : weight fp32->bf16 convert (nconv=256: wq+wp; 192: wq)
//   [nconv, nconv+64)  : FiLM GEMV (16 j per block)
//   [nconv+64, +512)   : GroupNorm stats
// Replaces 3 serialized launches; parts co-run across CUs.
// ---------------------------------------------------------------------------
__global__ __launch_bounds__(1024) void prep_kernel(
    const float* __restrict__ qkv_w, const float* __restrict__ proj_w,
    bf16* __restrict__ wq, bf16* __restrict__ wp,
    const float* __restrict__ emb, const float* __restrict__ emb_w,
    const float* __restrict__ emb_b, float* __restrict__ e_out,
    const float* __restrict__ x, float* __restrict__ mean_buf,
    float* __restrict__ rstd_buf, int nconv) {
  __shared__ float S[B_ * E_];       // 64 KB (film)
  __shared__ float ss[16], ssq[16];  // gn
  int bid = blockIdx.x;
  int tid = threadIdx.x;
  if (bid < nconv) {
    // ---- weight convert ----
    int i4 = bid * 1024 + tid;
    const int NQ4 = (3 * C_ * C_) / 4;  // 196608
    const float* src;
    unsigned short* dst;
    int off;
    if (i4 < NQ4) {
      src = qkv_w; dst = (unsigned short*)wq; off = i4;
    } else {
      src = proj_w; dst = (unsigned short*)wp; off = i4 - NQ4;
    }
    float4 v = *(const float4*)(src + (size_t)off * 4);
    uint2 pk = {cvtpk(v.x, v.y), cvtpk(v.z, v.w)};
    *(uint2*)(dst + (size_t)off * 4) = pk;
    return;
  }
  bid -= nconv;
  int wave = tid >> 6, lane = tid & 63;
  if (bid < 64) {
    // ---- FiLM GEMV: j = bid*16 + wave ----
    float4* S4 = (float4*)S;
    const float4* e4 = (const float4*)emb;
    for (int i = tid; i < (B_ * E_) / 4; i += 1024) {
      float4 v = e4[i];
      float4 o;
      o.x = v.x / (1.f + __expf(-v.x));
      o.y = v.y / (1.f + __expf(-v.y));
      o.z = v.z / (1.f + __expf(-v.z));
      o.w = v.w / (1.f + __expf(-v.w));
      S4[i] = o;
    }
    __syncthreads();
    int j = bid * 16 + wave;  // 0..1023
    const float4* w4p = (const float4*)(emb_w + (size_t)j * E_);
    float4 w4[4];
#pragma unroll
    for (int k = 0; k < 4; k++) w4[k] = w4p[k * 64 + lane];
    float bias = emb_b[j];
    for (int b = 0; b < B_; b++) {
      const float4* Sb = (const float4*)(S + b * E_);
      float acc = 0.f;
#pragma unroll
      for (int k = 0; k < 4; k++) {
        float4 s = Sb[k * 64 + lane];
        acc += w4[k].x * s.x + w4[k].y * s.y + w4[k].z * s.z + w4[k].w * s.w;
      }
#pragma unroll
      for (int off = 1; off < 64; off <<= 1) acc += __shfl_xor(acc, off, 64);
      if (lane == 0) e_out[b * (2 * C_) + j] = acc + bias;
    }
    return;
  }
  bid -= 64;
  // ---- GroupNorm stats: bg = bid ----
  {
    int bg = bid;
    const float4* b4 = (const float4*)(x + (size_t)bg * (CPG * T_));
    float s = 0.f, sq = 0.f;
#pragma unroll
    for (int p = 0; p < 4; p++) {
      float4 v = b4[p * 1024 + tid];
      s += v.x + v.y + v.z + v.w;
      sq += v.x * v.x + v.y * v.y + v.z * v.z + v.w * v.w;
    }
    for (int off = 32; off > 0; off >>= 1) {
      s += __shfl_down(s, off, 64);
      sq += __shfl_down(sq, off, 64);
    }
    if (lane == 0) { ss[wave] = s; ssq[wave] = sq; }
    __syncthreads();
    if (tid == 0) {
      float Sm = 0.f, Q = 0.f;
#pragma unroll
      for (int w = 0; w < 16; w++) { Sm += ss[w]; Q += ssq[w]; }
      const float inv_n = 1.f / (CPG * T_);
      float m = Sm * inv_n;
      float var = Q * inv_n - m * m;
      mean_buf[bg] = m;
      rstd_buf[bg] = rsqrtf(fmaxf(var, 0.f) + 1e-5f);
    }
  }
}

// K0b: single-buffer conversion (path B: wp late into q_buf).
__global__ __launch_bounds__(256) void convert_one(
    const float* __restrict__ src, bf16* __restrict__ dst) {
  int i4 = blockIdx.x * 256 + threadIdx.x;
  float4 v = *(const float4*)(src + (size_t)i4 * 4);
  uint2 pk = {cvtpk(v.x, v.y), cvtpk(v.z, v.w)};
  *(uint2*)((unsigned short*)dst + (size_t)i4 * 4) = pk;
}

// ---------------------------------------------------------------------------
// K3: normalize + FiLM -> h as bf16 [bl][t][C] (t-major!) via LDS transpose.
// ---------------------------------------------------------------------------
__global__ __launch_bounds__(256) void norm_film_t2(
    const float* __restrict__ x, const float* __restrict__ mean_buf,
    const float* __restrict__ rstd_buf, const float* __restrict__ gamma,
    const float* __restrict__ beta, const float* __restrict__ e_buf,
    bf16* __restrict__ h, int b0) {
  __shared__ unsigned short S[64][66];
  __shared__ float pm[64], pr[64], pa[64];
  int t0 = blockIdx.x * 64;
  int c0 = blockIdx.y * 64;
  int bl = blockIdx.z;
  int b = b0 + bl;
  int tid = threadIdx.x;
  if (tid < 64) {
    int c = c0 + tid;
    int g = c >> 4;
    float m = mean_buf[b * G_ + g];
    float r = rstd_buf[b * G_ + g];
    float sc = 1.f + e_buf[b * 2 * C_ + c];
    float sh = e_buf[b * 2 * C_ + C_ + c];
    pm[tid] = m;
    pr[tid] = r * gamma[c] * sc;
    pa[tid] = beta[c] * sc + sh;
  }
  __syncthreads();
  const float* xb = x + ((size_t)b * C_ + c0) * T_ + t0;
#pragma unroll
  for (int p = 0; p < 4; p++) {
    int i = p * 256 + tid;
    int cl = i >> 4, t4 = (i & 15) * 4;
    float4 v = *(const float4*)(xb + (size_t)cl * T_ + t4);
    float m = pm[cl], r = pr[cl], ad = pa[cl];
    *(unsigned int*)&S[cl][t4] = cvtpk((v.x - m) * r + ad, (v.y - m) * r + ad);
    *(unsigned int*)&S[cl][t4 + 2] =
        cvtpk((v.z - m) * r + ad, (v.w - m) * r + ad);
  }
  __syncthreads();
  unsigned short* hg = (unsigned short*)h + ((size_t)bl * T_ + t0) * C_ + c0;
#pragma unroll
  for (int p = 0; p < 2; p++) {
    int i = p * 256 + tid;
    int tr = i >> 3, c8 = (i & 7) * 8;
    unsigned int w0 = (unsigned int)S[c8 + 0][tr] |
                      ((unsigned int)S[c8 + 1][tr] << 16);
    unsigned int w1 = (unsigned int)S[c8 + 2][tr] |
                      ((unsigned int)S[c8 + 3][tr] << 16);
    unsigned int w2 = (unsigned int)S[c8 + 4][tr] |
                      ((unsigned int)S[c8 + 5][tr] << 16);
    unsigned int w3 = (unsigned int)S[c8 + 6][tr] |
                      ((unsigned int)S[c8 + 7][tr] << 16);
    int4 pk = {(int)w0, (int)w1, (int)w2, (int)w3};
    *(int4*)(hg + (size_t)tr * C_ + c8) = pk;
  }
}

// ---------------------------------------------------------------------------
// K4: QKV GEMM v5 (unchanged): dbuf prefetch + XCD-group swizzle.
// ---------------------------------------------------------------------------
#define ST_STRIDE 264
__global__ __launch_bounds__(256) void qkv_gemm_mfma5(
    const bf16* __restrict__ h, const bf16* __restrict__ wq,
    const float* __restrict__ qkv_b, bf16* __restrict__ qb,
    bf16* __restrict__ kb, bf16* __restrict__ vb, int ngroups) {
  __shared__ __align__(16) unsigned short LB[40960];  // 81920 B (2 bufs)
  int bid = blockIdx.x;
  int g, o;
  if ((ngroups & 7) == 0) {
    int xcd = bid & 7, j = bid >> 3;
    o = j % 24;
    int slot = j / 24;
    g = slot * 8 + xcd;
  } else {
    o = bid % 24;
    g = bid / 24;
  }
  int tst = g & 3;      // t-supertile (256 rows)
  int bl = g >> 2;
  int o0 = o * 64;
  int tb = tst * 256;
  int tid = threadIdx.x;
  int wave = tid >> 6, lane = tid & 63;
  int col = lane & 15, quad = lane >> 4;
  int cs = col & 7;
  int w64 = wave * 64;
  const unsigned short* hg = (const unsigned short*)h + (size_t)bl * T_ * C_;
  const unsigned short* wg = (const unsigned short*)wq;
  char* lds = (char*)LB;
  f32x4 acc[4][4];
  for (int i = 0; i < 4; i++)
    for (int j2 = 0; j2 < 4; j2++) acc[i][j2] = f32x4{0, 0, 0, 0};

#define QSTAGE(buf, c0_)                                                      \
  do {                                                                        \
    _Pragma("unroll") for (int p = 0; p < 8; p++) {                           \
      int i_ = p * 256 + tid;                                                 \
      int row_ = i_ >> 3;                                                     \
      int sci_ = (i_ & 7) ^ (row_ & 7);                                       \
      gload16(hg + (size_t)(tb + row_) * C_ + (c0_) + sci_ * 8,               \
              lds + (buf) * 40960 + (p * 256 + wave * 64) * 16);              \
    }                                                                         \
    _Pragma("unroll") for (int p = 0; p < 2; p++) {                           \
      int i_ = p * 256 + tid;                                                 \
      int row_ = i_ >> 3;                                                     \
      int sci_ = (i_ & 7) ^ (row_ & 7);                                       \
      gload16(wg + (size_t)(o0 + row_) * C_ + (c0_) + sci_ * 8,               \
              lds + (buf) * 40960 + 32768 + (p * 256 + wave * 64) * 16);      \
    }                                                                         \
  } while (0)

  QSTAGE(0, 0);
  __syncthreads();
  int cur = 0;
  for (int kst = 0; kst < 8; kst++) {
    if (kst < 7) QSTAGE(cur ^ 1, (kst + 1) * 64);  // async prefetch
    const unsigned short* hb = LB + cur * 20480;
    const unsigned short* wb2 = hb + 16384;
    __builtin_amdgcn_s_setprio(1);
#pragma unroll
    for (int ks = 0; ks < 2; ks++) {
      short8 af[4], bfr[4];
#pragma unroll
      for (int mt = 0; mt < 4; mt++)
        af[mt] = *(const short8*)&hb[(w64 + mt * 16 + col) * 64 +
                                     (((ks * 4 + quad) ^ cs) << 3)];
#pragma unroll
      for (int nt = 0; nt < 4; nt++)
        bfr[nt] = *(const short8*)&wb2[(nt * 16 + col) * 64 +
                                       (((ks * 4 + quad) ^ cs) << 3)];
#pragma unroll
      for (int mt = 0; mt < 4; mt++)
#pragma unroll
        for (int nt = 0; nt < 4; nt++)
          acc[mt][nt] = __builtin_amdgcn_mfma_f32_16x16x32_bf16(
              af[mt], bfr[nt], acc[mt][nt], 0, 0, 0);
    }
    __builtin_amdgcn_s_setprio(0);
    __syncthreads();  // drains this wave's prefetch + releases cur buffer
    cur ^= 1;
  }
#undef QSTAGE
  int sec = (o0 >> 6) % 3;
  int hd = o0 / 192;
  const float s = 0.35355339059327373f;       // 64^-0.25
  const float sq = s * 1.4426950408889634f;   // fold log2(e) into q
  if (sec < 2) {
    bf16* dst = (sec == 0) ? qb : kb;
    float sc = (sec == 0) ? sq : s;
    size_t hb2 = (size_t)(bl * NH + hd) * T_ * CH;
    for (int mt = 0; mt < 4; mt++) {
      for (int r = 0; r < 4; r++) {
        int t = tb + w64 + mt * 16 + quad * 4 + r;
        for (int nt = 0; nt < 4; nt++) {
          int ch = nt * 16 + col;
          dst[hb2 + (size_t)t * CH + ch] =
              f2b_fast((acc[mt][nt][r] + qkv_b[o0 + ch]) * sc);
        }
      }
    }
  } else {
    // staging LDS now dead; reuse as St[64][264]
    for (int mt = 0; mt < 4; mt++) {
      for (int r = 0; r < 4; r++) {
        int tl = w64 + mt * 16 + quad * 4 + r;
        for (int nt = 0; nt < 4; nt++) {
          int ch = nt * 16 + col;
          LB[ch * ST_STRIDE + tl] =
              fbits_fast(acc[mt][nt][r] + qkv_b[o0 + ch]);
        }
      }
    }
    __syncthreads();
    int rr = tid >> 2, csx = (tid & 3) * 64;
    size_t base = ((size_t)(bl * NH + hd) * CH + rr) * T_ + tb + csx;
    unsigned short* vg = (unsigned short*)vb;
    for (int j2 = 0; j2 < 8; j2++)
      *(int4*)(vg + base + j2 * 8) =
          *(const int4*)&LB[rr * ST_STRIDE + csx + j2 * 8];
  }
}

// ---------------------------------------------------------------------------
// K5: flash attention v9.
//  - V fragments loaded DIRECTLY global->VGPR (16B/lane contiguous, ch-major
//    v_buf; L2-resident via head-per-XCD swizzle). Staging L2-fit data
//    through LDS was pure overhead: removes 2 gload_lds/thread + 8
//    ds_read_b128/wave per tile; barrier drain depth 4 -> 2 loads.
//    V loads issued BEFORE the K prefetch so PV's wait is vmcnt(2), keeping
//    the K prefetch in flight; QK+softmax (~300cy) covers the L2 latency.
//  - zero-C MFMA init (St = mfma(ak,bq,z4)): deletes 32 v_mov/tile.
//  - LDS 24576 B (K dbuf 16K + Pst 8K).
// ---------------------------------------------------------------------------
__global__ __launch_bounds__(256, 4) void attn_mfma9(
    const bf16* __restrict__ qb, const bf16* __restrict__ kb,
    const bf16* __restrict__ vb, bf16* __restrict__ a, int nbh) {
  __shared__ __align__(16) unsigned short LB[12288];  // 24576 B
  int bid = blockIdx.x;
  int bh = bid % nbh;           // nbh mult of 8 -> same-head tiles share XCD L2
  int qt0 = (bid / nbh) * 128;
  int tid = threadIdx.x;
  int wave = tid >> 6, lane = tid & 63;
  int col = lane & 15, quad = lane >> 4;
  int cs = col & 7;             // K read-side swizzle key
  int ps = (col >> 1) & 3;      // Pst swizzle key (bank-quad spread, 2-way)
  const unsigned short* qg = (const unsigned short*)qb;
  const unsigned short* kg = (const unsigned short*)kb;
  const unsigned short* vg = (const unsigned short*)vb;
  const size_t tmaj = (size_t)bh * T_ * CH;
  const size_t cmaj = (size_t)bh * CH * T_;
  char* lds = (char*)LB;

  int qrow = qt0 + wave * 16 + col;
  short8 bq0[2], bq1[2];
#pragma unroll
  for (int u = 0; u < 2; u++) {
    const unsigned short* qp = qg + tmaj + (size_t)(qrow + u * 64) * CH;
    bq0[u] = *(const short8*)(qp + quad * 8);
    bq1[u] = *(const short8*)(qp + 32 + quad * 8);
  }
  f32x4 Ot0[4], Ot1[4];
#pragma unroll
  for (int mt = 0; mt < 4; mt++) {
    Ot0[mt] = f32x4{0, 0, 0, 0};
    Ot1[mt] = f32x4{0, 0, 0, 0};
  }
  const short ob = (short)0x3F80;  // bf16 1.0
  short8 ones = {ob, ob, ob, ob, ob, ob, ob, ob};
  f32x4 La0 = f32x4{0, 0, 0, 0}, La1 = f32x4{0, 0, 0, 0};
  const f32x4 z4 = {0.f, 0.f, 0.f, 0.f};
  unsigned short* pw0 = LB + 8192 + wave * 512 + col * 32;
  unsigned short* pw1 = pw0 + 2048;

#define KSTAGE(buf, tt)                                                       \
  do {                                                                        \
    int s0_ = (tt) * 64;                                                      \
    const unsigned short* kt_ = kg + tmaj + (size_t)s0_ * CH;                 \
    _Pragma("unroll") for (int cc = 0; cc < 2; cc++) {                        \
      int i_ = cc * 256 + tid;                                                \
      int row_ = i_ >> 3;                                                     \
      int sci_ = (i_ & 7) ^ (row_ & 7);                                       \
      gload16(kt_ + (size_t)row_ * CH + sci_ * 8,                             \
              lds + (buf) * 8192 + (cc * 256 + wave * 64) * 16);              \
    }                                                                         \
  } while (0)

  KSTAGE(0, 0);
  __syncthreads();
  int cur = 0;
  for (int t = 0; t < 16; t++) {
    int s0 = t * 64;
    // V fragments direct from global (issued FIRST: PV waits vmcnt(2) only)
    short8 avv[8];
#pragma unroll
    for (int kc = 0; kc < 2; kc++)
#pragma unroll
      for (int mt = 0; mt < 4; mt++)
        avv[kc * 4 + mt] = *(const short8*)(
            vg + cmaj + (size_t)(mt * 16 + col) * T_ + s0 + kc * 32 + quad * 8);
    if (t < 15) KSTAGE(cur ^ 1, t + 1);  // async prefetch, no wait
    const char* ksb = lds + cur * 8192;
    // ---- QK^T for both q-halves, K fragments read once, zero-C init ----
    f32x4 St0[4], St1[4];
    __builtin_amdgcn_s_setprio(1);
#pragma unroll
    for (int mt = 0; mt < 4; mt++) {
      int rb = (mt * 16 + col) * 128;
      short8 ak0 = *(const short8*)(ksb + rb + ((quad ^ cs) << 4));
      short8 ak1 = *(const short8*)(ksb + rb + (((quad + 4) ^ cs) << 4));
      St0[mt] = __builtin_amdgcn_mfma_f32_16x16x32_bf16(ak0, bq0[0], z4, 0, 0, 0);
      St1[mt] = __builtin_amdgcn_mfma_f32_16x16x32_bf16(ak0, bq0[1], z4, 0, 0, 0);
      St0[mt] = __builtin_amdgcn_mfma_f32_16x16x32_bf16(ak1, bq1[0], St0[mt], 0, 0, 0);
      St1[mt] = __builtin_amdgcn_mfma_f32_16x16x32_bf16(ak1, bq1[1], St1[mt], 0, 0, 0);
    }
    __builtin_amdgcn_s_setprio(0);
    // ---- softmax (exp2; q carries log2e). l via ones-MFMA below ----
#pragma unroll
    for (int mt = 0; mt < 4; mt++)
#pragma unroll
      for (int r = 0; r < 4; r++) {
        St0[mt][r] = __builtin_amdgcn_exp2f(St0[mt][r]);
        St1[mt][r] = __builtin_amdgcn_exp2f(St1[mt][r]);
      }
    // ---- PV: V from registers, shared across both u ----
#pragma unroll
    for (int kc = 0; kc < 2; kc++) {
#pragma unroll
      for (int mh = 0; mh < 2; mh++) {
        int mt = kc * 2 + mh;
        int wsw = (((2 * mh + (quad >> 1)) ^ ps) << 3) + (quad & 1) * 4;
        uint2 k0 = {cvtpk(St0[mt][0], St0[mt][1]),
                    cvtpk(St0[mt][2], St0[mt][3])};
        uint2 k1 = {cvtpk(St1[mt][0], St1[mt][1]),
                    cvtpk(St1[mt][2], St1[mt][3])};
        *(uint2*)(pw0 + wsw) = k0;
        *(uint2*)(pw1 + wsw) = k1;
      }
      int rsw = (quad ^ ps) << 3;
      short8 bp0 = *(const short8*)(pw0 + rsw);
      short8 bp1 = *(const short8*)(pw1 + rsw);
      __builtin_amdgcn_s_setprio(1);
      La0 = __builtin_amdgcn_mfma_f32_16x16x32_bf16(ones, bp0, La0, 0, 0, 0);
      La1 = __builtin_amdgcn_mfma_f32_16x16x32_bf16(ones, bp1, La1, 0, 0, 0);
#pragma unroll
      for (int mt = 0; mt < 4; mt++) {
        Ot0[mt] = __builtin_amdgcn_mfma_f32_16x16x32_bf16(avv[kc * 4 + mt],
                                                          bp0, Ot0[mt], 0, 0, 0);
        Ot1[mt] = __builtin_amdgcn_mfma_f32_16x16x32_bf16(avv[kc * 4 + mt],
                                                          bp1, Ot1[mt], 0, 0, 0);
      }
      __builtin_amdgcn_s_setprio(0);
    }
    __syncthreads();  // drains this wave's K prefetch + syncs buffers
    cur ^= 1;
  }
#undef KSTAGE
  // epilogue: l = La[0] (every C element of the ones-MFMA holds the full sum)
  int bl = bh >> 3, hd = bh & 7;
  unsigned short* ag = (unsigned short*)a;
#pragma unroll
  for (int u = 0; u < 2; u++) {
    float inv = 1.f / ((u == 0) ? La0[0] : La1[0]);
    const f32x4* Ou = (u == 0) ? Ot0 : Ot1;
    size_t rowb = ((size_t)bl * T_ + qrow + u * 64) * C_ + hd * CH;
#pragma unroll
    for (int mt = 0; mt < 4; mt++) {
      uint2 pk = {cvtpk(Ou[mt][0] * inv, Ou[mt][1] * inv),
                  cvtpk(Ou[mt][2] * inv, Ou[mt][3] * inv)};
      *(uint2*)(ag + rowb + mt * 16 + quad * 4) = pk;
    }
  }
}

// ---------------------------------------------------------------------------
// K6: proj GEMM + residual v4 (unchanged): dbuf prefetch.
// ---------------------------------------------------------------------------
__global__ __launch_bounds__(256) void proj_mfma4(
    const bf16* __restrict__ a, const bf16* __restrict__ wp,
    const float* __restrict__ proj_b, const float* __restrict__ x,
    float* __restrict__ out, int b0) {
  __shared__ __align__(16) unsigned short LB[16384];  // 32768 B (2 bufs)
  int bl = blockIdx.z;
  int b = b0 + bl;
  int o0 = blockIdx.y * 64;
  int t0 = blockIdx.x * 64;
  int tid = threadIdx.x;
  int wave = tid >> 6, lane = tid & 63;
  int col = lane & 15, quad = lane >> 4;
  int cs = col & 7;
  int m0 = wave * 16;
  const unsigned short* ag = (const unsigned short*)a + (size_t)bl * T_ * C_;
  const unsigned short* wg = (const unsigned short*)wp;
  char* lds = (char*)LB;
  f32x4 acc[4] = {f32x4{0,0,0,0}, f32x4{0,0,0,0}, f32x4{0,0,0,0}, f32x4{0,0,0,0}};

#define PSTAGE(buf, c0_)                                                      \
  do {                                                                        \
    _Pragma("unroll") for (int cc = 0; cc < 2; cc++) {                        \
      int i_ = cc * 256 + tid;                                                \
      int row_ = i_ >> 3;                                                     \
      int sci_ = (i_ & 7) ^ (row_ & 7);                                       \
      int wb_ = (cc * 256 + wave * 64) * 16;                                  \
      gload16(ag + (size_t)(t0 + row_) * C_ + (c0_) + sci_ * 8,               \
              lds + (buf) * 16384 + wb_);                                     \
      gload16(wg + (size_t)(o0 + row_) * C_ + (c0_) + sci_ * 8,               \
              lds + (buf) * 16384 + 8192 + wb_);                              \
    }                                                                         \
  } while (0)

  PSTAGE(0, 0);
  __syncthreads();
  int cur = 0;
  for (int kst = 0; kst < 8; kst++) {
    if (kst < 7) PSTAGE(cur ^ 1, (kst + 1) * 64);  // async prefetch
    const unsigned short* ab = LB + cur * 8192;
    const unsigned short* wb2 = ab + 4096;
    __builtin_amdgcn_s_setprio(1);
#pragma unroll
    for (int ks = 0; ks < 2; ks++) {
      short8 aw = *(const short8*)&wb2[(m0 + col) * 64 +
                                       (((ks * 4 + quad) ^ cs) << 3)];
#pragma unroll
      for (int nt = 0; nt < 4; nt++) {
        short8 ba = *(const short8*)&ab[(nt * 16 + col) * 64 +
                                        (((ks * 4 + quad) ^ cs) << 3)];
        acc[nt] = __builtin_amdgcn_mfma_f32_16x16x32_bf16(aw, ba, acc[nt], 0, 0, 0);
      }
    }
    __builtin_amdgcn_s_setprio(0);
    __syncthreads();
    cur ^= 1;
  }
#undef PSTAGE
  for (int r = 0; r < 4; r++) {
    int o = o0 + m0 + quad * 4 + r;
    float bias = proj_b[o];
    size_t rowb = ((size_t)b * C_ + o) * T_ + t0;
    for (int nt = 0; nt < 4; nt++) {
      int t = nt * 16 + col;
      out[rowb + t] = x[rowb + t] + acc[nt][r] + bias;
    }
  }
}

// ---------------------------------------------------------------------------
// Host. Workspace plans (A: all in ws; B: scratch in d_out; C: legacy chunked).
// ---------------------------------------------------------------------------
extern "C" void kernel_launch(void* const* d_in, const int* in_sizes, int n_in,
                              void* d_out, int out_size, void* d_ws,
                              size_t ws_size, hipStream_t stream) {
  const float* x      = (const float*)d_in[0];
  const float* emb    = (const float*)d_in[1];
  const float* gamma  = (const float*)d_in[2];
  const float* beta   = (const float*)d_in[3];
  const float* emb_w  = (const float*)d_in[4];
  const float* emb_b  = (const float*)d_in[5];
  const float* qkv_w  = (const float*)d_in[6];
  const float* qkv_b  = (const float*)d_in[7];
  const float* proj_w = (const float*)d_in[8];
  const float* proj_b = (const float*)d_in[9];
  float* out = (float*)d_out;

  const size_t BUF16 = (size_t)16 * CT * sizeof(bf16);   // 16 MiB per buffer
  const size_t FULL4 = 4 * BUF16;                        // 64 MiB
  const size_t SCR   = 131072 + (size_t)4 * C_ * C_ * sizeof(bf16);

  if (ws_size >= FULL4) {
    // ---- paths A/B: single full-batch pass ----
    bf16* h_buf = (bf16*)d_ws;               // also 'a' after attn
    bf16* q_buf = h_buf + BUF16 / sizeof(bf16);
    bf16* k_buf = q_buf + BUF16 / sizeof(bf16);
    bf16* v_buf = k_buf + BUF16 / sizeof(bf16);
    bool inWs = ws_size >= FULL4 + SCR;
    char* scr = inWs ? ((char*)d_ws + FULL4) : (char*)d_out;
    float* e_buf    = (float*)scr;
    float* mean_buf = e_buf + B_ * 2 * C_;
    float* rstd_buf = mean_buf + B_ * G_;
    bf16*  wq_bf    = (bf16*)(scr + 131072);
    bf16*  wp_bf;
    int nconv;
    if (inWs) {
      wp_bf = wq_bf + (size_t)3 * C_ * C_;
      nconv = 256;            // wq + wp
    } else {
      wp_bf = q_buf;          // filled after attn (q dead by then)
      nconv = 192;            // wq only (192*1024 = 3C^2/4 float4s)
    }
    prep_kernel<<<dim3(nconv + 64 + 512), 1024, 0, stream>>>(
        qkv_w, proj_w, wq_bf, wp_bf, emb, emb_w, emb_b, e_buf, x, mean_buf,
        rstd_buf, nconv);
    norm_film_t2<<<dim3(16, 8, 16), 256, 0, stream>>>(
        x, mean_buf, rstd_buf, gamma, beta, e_buf, h_buf, 0);
    qkv_gemm_mfma5<<<dim3(24 * 64), 256, 0, stream>>>(h_buf, wq_bf, qkv_b,
                                                      q_buf, k_buf, v_buf, 64);
    attn_mfma9<<<dim3(8 * 128), 256, 0, stream>>>(q_buf, k_buf, v_buf, h_buf,
                                                  128);
    if (!inWs)
      convert_one<<<dim3(256), 256, 0, stream>>>(proj_w, wp_bf);
    proj_mfma4<<<dim3(16, 8, 16), 256, 0, stream>>>(h_buf, wp_bf, proj_b, x,
                                                    out, 0);
  } else {
    // ---- path C: legacy chunked layout ----
    float* e_buf    = (float*)d_ws;
    float* mean_buf = e_buf + B_ * 2 * C_;
    float* rstd_buf = mean_buf + B_ * G_;
    bf16*  wq_bf    = (bf16*)((char*)d_ws + 131072);
    bf16*  wp_bf    = wq_bf + (size_t)3 * C_ * C_;
    bf16* pool = (bf16*)((char*)d_ws + SCR);
    size_t avail = ws_size > SCR ? ws_size - SCR : 0;
    int NB = 16;
    while (NB > 1 && (size_t)4 * NB * CT * sizeof(bf16) > avail) NB >>= 1;
    bf16* h_buf = pool;
    bf16* q_buf = h_buf + (size_t)NB * CT;
    bf16* k_buf = q_buf + (size_t)NB * CT;
    bf16* v_buf = k_buf + (size_t)NB * CT;

    prep_kernel<<<dim3(256 + 64 + 512), 1024, 0, stream>>>(
        qkv_w, proj_w, wq_bf, wp_bf, emb, emb_w, emb_b, e_buf, x, mean_buf,
        rstd_buf, 256);
    for (int b0 = 0; b0 < B_; b0 += NB) {
      norm_film_t2<<<dim3(16, 8, NB), 256, 0, stream>>>(
          x, mean_buf, rstd_buf, gamma, beta, e_buf, h_buf, b0);
      qkv_gemm_mfma5<<<dim3(24 * 4 * NB), 256, 0, stream>>>(
          h_buf, wq_bf, qkv_b, q_buf, k_buf, v_buf, 4 * NB);
      int nbh = NB * NH;
      attn_mfma9<<<dim3(8 * nbh), 256, 0, stream>>>(q_buf, k_buf, v_buf,
                                                    h_buf, nbh);
      proj_mfma4<<<dim3(16, 8, NB), 256, 0, stream>>>(h_buf, wp_bf, proj_b, x,
                                                      out, b0);
    }
  }
}

// Round 9
// 206.419 us; speedup vs baseline: 1.4806x; 1.4806x over previous
//
#include <hip/hip_runtime.h>
#include <hip/hip_bf16.h>

typedef __hip_bfloat16 bf16;
typedef __attribute__((ext_vector_type(8))) short short8;
typedef __attribute__((ext_vector_type(4))) float f32x4;
typedef __attribute__((ext_vector_type(4))) unsigned short us4;
typedef __attribute__((ext_vector_type(2))) unsigned short us2;

#define B_  16
#define C_  512
#define T_  1024
#define G_  32
#define CPG 16
#define E_  1024
#define NH  8
#define CH  64
#define CT  (C_ * T_)   // 524288 elements per batch (1 MiB as bf16)

__device__ __forceinline__ float b2f(bf16 v) { return __bfloat162float(v); }
// fast RNE f32->bf16 (finite inputs only)
__device__ __forceinline__ unsigned short fbits_fast(float v) {
  unsigned int u = __builtin_bit_cast(unsigned int, v);
  u += 0x7fff + ((u >> 16) & 1);
  return (unsigned short)(u >> 16);
}
__device__ __forceinline__ bf16 f2b_fast(float v) {
  unsigned short s = fbits_fast(v);
  return *reinterpret_cast<bf16*>(&s);
}
// packed f32x2 -> bf16x2 in ONE VALU op (RNE, matches fbits_fast on finites)
__device__ __forceinline__ unsigned int cvtpk(float lo, float hi) {
  unsigned int r;
  asm("v_cvt_pk_bf16_f32 %0, %1, %2" : "=v"(r) : "v"(lo), "v"(hi));
  return r;
}

// async global->LDS, 16B per lane; LDS dest must be wave-uniform base; data
// lands at base + lane*16.
__device__ __forceinline__ void gload16(const void* g, void* l) {
  __builtin_amdgcn_global_load_lds(
      (const __attribute__((address_space(1))) void*)g,
      (__attribute__((address_space(3))) void*)l, 16, 0, 0);
}

// ---------------------------------------------------------------------------
// K0: fused prep kernel (1024 thr): blockIdx partition
//   [0, nconv)         : weight fp32->bf16 convert (nconv=256: wq+wp; 192: wq)
//   [nconv, nconv+64)  : FiLM GEMV (16 j per block)
//   [nconv+64, +512)   : GroupNorm stats
// ---------------------------------------------------------------------------
__global__ __launch_bounds__(1024) void prep_kernel(
    const float* __restrict__ qkv_w, const float* __restrict__ proj_w,
    bf16* __restrict__ wq, bf16* __restrict__ wp,
    const float* __restrict__ emb, const float* __restrict__ emb_w,
    const float* __restrict__ emb_b, float* __restrict__ e_out,
    const float* __restrict__ x, float* __restrict__ mean_buf,
    float* __restrict__ rstd_buf, int nconv) {
  __shared__ float S[B_ * E_];       // 64 KB (film)
  __shared__ float ss[16], ssq[16];  // gn
  int bid = blockIdx.x;
  int tid = threadIdx.x;
  if (bid < nconv) {
    // ---- weight convert ----
    int i4 = bid * 1024 + tid;
    const int NQ4 = (3 * C_ * C_) / 4;  // 196608
    const float* src;
    unsigned short* dst;
    int off;
    if (i4 < NQ4) {
      src = qkv_w; dst = (unsigned short*)wq; off = i4;
    } else {
      src = proj_w; dst = (unsigned short*)wp; off = i4 - NQ4;
    }
    float4 v = *(const float4*)(src + (size_t)off * 4);
    uint2 pk = {cvtpk(v.x, v.y), cvtpk(v.z, v.w)};
    *(uint2*)(dst + (size_t)off * 4) = pk;
    return;
  }
  bid -= nconv;
  int wave = tid >> 6, lane = tid & 63;
  if (bid < 64) {
    // ---- FiLM GEMV: j = bid*16 + wave ----
    float4* S4 = (float4*)S;
    const float4* e4 = (const float4*)emb;
    for (int i = tid; i < (B_ * E_) / 4; i += 1024) {
      float4 v = e4[i];
      float4 o;
      o.x = v.x / (1.f + __expf(-v.x));
      o.y = v.y / (1.f + __expf(-v.y));
      o.z = v.z / (1.f + __expf(-v.z));
      o.w = v.w / (1.f + __expf(-v.w));
      S4[i] = o;
    }
    __syncthreads();
    int j = bid * 16 + wave;  // 0..1023
    const float4* w4p = (const float4*)(emb_w + (size_t)j * E_);
    float4 w4[4];
#pragma unroll
    for (int k = 0; k < 4; k++) w4[k] = w4p[k * 64 + lane];
    float bias = emb_b[j];
    for (int b = 0; b < B_; b++) {
      const float4* Sb = (const float4*)(S + b * E_);
      float acc = 0.f;
#pragma unroll
      for (int k = 0; k < 4; k++) {
        float4 s = Sb[k * 64 + lane];
        acc += w4[k].x * s.x + w4[k].y * s.y + w4[k].z * s.z + w4[k].w * s.w;
      }
#pragma unroll
      for (int off = 1; off < 64; off <<= 1) acc += __shfl_xor(acc, off, 64);
      if (lane == 0) e_out[b * (2 * C_) + j] = acc + bias;
    }
    return;
  }
  bid -= 64;
  // ---- GroupNorm stats: bg = bid ----
  {
    int bg = bid;
    const float4* b4 = (const float4*)(x + (size_t)bg * (CPG * T_));
    float s = 0.f, sq = 0.f;
#pragma unroll
    for (int p = 0; p < 4; p++) {
      float4 v = b4[p * 1024 + tid];
      s += v.x + v.y + v.z + v.w;
      sq += v.x * v.x + v.y * v.y + v.z * v.z + v.w * v.w;
    }
    for (int off = 32; off > 0; off >>= 1) {
      s += __shfl_down(s, off, 64);
      sq += __shfl_down(sq, off, 64);
    }
    if (lane == 0) { ss[wave] = s; ssq[wave] = sq; }
    __syncthreads();
    if (tid == 0) {
      float Sm = 0.f, Q = 0.f;
#pragma unroll
      for (int w = 0; w < 16; w++) { Sm += ss[w]; Q += ssq[w]; }
      const float inv_n = 1.f / (CPG * T_);
      float m = Sm * inv_n;
      float var = Q * inv_n - m * m;
      mean_buf[bg] = m;
      rstd_buf[bg] = rsqrtf(fmaxf(var, 0.f) + 1e-5f);
    }
  }
}

// K0b: single-buffer conversion (path B: wp late into q_buf).
__global__ __launch_bounds__(256) void convert_one(
    const float* __restrict__ src, bf16* __restrict__ dst) {
  int i4 = blockIdx.x * 256 + threadIdx.x;
  float4 v = *(const float4*)(src + (size_t)i4 * 4);
  uint2 pk = {cvtpk(v.x, v.y), cvtpk(v.z, v.w)};
  *(uint2*)((unsigned short*)dst + (size_t)i4 * 4) = pk;
}

// ---------------------------------------------------------------------------
// K3: normalize + FiLM -> h as bf16 [bl][t][C] (t-major!) via LDS transpose.
// ---------------------------------------------------------------------------
__global__ __launch_bounds__(256) void norm_film_t2(
    const float* __restrict__ x, const float* __restrict__ mean_buf,
    const float* __restrict__ rstd_buf, const float* __restrict__ gamma,
    const float* __restrict__ beta, const float* __restrict__ e_buf,
    bf16* __restrict__ h, int b0) {
  __shared__ unsigned short S[64][66];
  __shared__ float pm[64], pr[64], pa[64];
  int t0 = blockIdx.x * 64;
  int c0 = blockIdx.y * 64;
  int bl = blockIdx.z;
  int b = b0 + bl;
  int tid = threadIdx.x;
  if (tid < 64) {
    int c = c0 + tid;
    int g = c >> 4;
    float m = mean_buf[b * G_ + g];
    float r = rstd_buf[b * G_ + g];
    float sc = 1.f + e_buf[b * 2 * C_ + c];
    float sh = e_buf[b * 2 * C_ + C_ + c];
    pm[tid] = m;
    pr[tid] = r * gamma[c] * sc;
    pa[tid] = beta[c] * sc + sh;
  }
  __syncthreads();
  const float* xb = x + ((size_t)b * C_ + c0) * T_ + t0;
#pragma unroll
  for (int p = 0; p < 4; p++) {
    int i = p * 256 + tid;
    int cl = i >> 4, t4 = (i & 15) * 4;
    float4 v = *(const float4*)(xb + (size_t)cl * T_ + t4);
    float m = pm[cl], r = pr[cl], ad = pa[cl];
    *(unsigned int*)&S[cl][t4] = cvtpk((v.x - m) * r + ad, (v.y - m) * r + ad);
    *(unsigned int*)&S[cl][t4 + 2] =
        cvtpk((v.z - m) * r + ad, (v.w - m) * r + ad);
  }
  __syncthreads();
  unsigned short* hg = (unsigned short*)h + ((size_t)bl * T_ + t0) * C_ + c0;
#pragma unroll
  for (int p = 0; p < 2; p++) {
    int i = p * 256 + tid;
    int tr = i >> 3, c8 = (i & 7) * 8;
    unsigned int w0 = (unsigned int)S[c8 + 0][tr] |
                      ((unsigned int)S[c8 + 1][tr] << 16);
    unsigned int w1 = (unsigned int)S[c8 + 2][tr] |
                      ((unsigned int)S[c8 + 3][tr] << 16);
    unsigned int w2 = (unsigned int)S[c8 + 4][tr] |
                      ((unsigned int)S[c8 + 5][tr] << 16);
    unsigned int w3 = (unsigned int)S[c8 + 6][tr] |
                      ((unsigned int)S[c8 + 7][tr] << 16);
    int4 pk = {(int)w0, (int)w1, (int)w2, (int)w3};
    *(int4*)(hg + (size_t)tr * C_ + c8) = pk;
  }
}

// ---------------------------------------------------------------------------
// K4: QKV GEMM v5 (unchanged): dbuf prefetch + XCD-group swizzle.
// ---------------------------------------------------------------------------
#define ST_STRIDE 264
__global__ __launch_bounds__(256) void qkv_gemm_mfma5(
    const bf16* __restrict__ h, const bf16* __restrict__ wq,
    const float* __restrict__ qkv_b, bf16* __restrict__ qb,
    bf16* __restrict__ kb, bf16* __restrict__ vb, int ngroups) {
  __shared__ __align__(16) unsigned short LB[40960];  // 81920 B (2 bufs)
  int bid = blockIdx.x;
  int g, o;
  if ((ngroups & 7) == 0) {
    int xcd = bid & 7, j = bid >> 3;
    o = j % 24;
    int slot = j / 24;
    g = slot * 8 + xcd;
  } else {
    o = bid % 24;
    g = bid / 24;
  }
  int tst = g & 3;      // t-supertile (256 rows)
  int bl = g >> 2;
  int o0 = o * 64;
  int tb = tst * 256;
  int tid = threadIdx.x;
  int wave = tid >> 6, lane = tid & 63;
  int col = lane & 15, quad = lane >> 4;
  int cs = col & 7;
  int w64 = wave * 64;
  const unsigned short* hg = (const unsigned short*)h + (size_t)bl * T_ * C_;
  const unsigned short* wg = (const unsigned short*)wq;
  char* lds = (char*)LB;
  f32x4 acc[4][4];
  for (int i = 0; i < 4; i++)
    for (int j2 = 0; j2 < 4; j2++) acc[i][j2] = f32x4{0, 0, 0, 0};

#define QSTAGE(buf, c0_)                                                      \
  do {                                                                        \
    _Pragma("unroll") for (int p = 0; p < 8; p++) {                           \
      int i_ = p * 256 + tid;                                                 \
      int row_ = i_ >> 3;                                                     \
      int sci_ = (i_ & 7) ^ (row_ & 7);                                       \
      gload16(hg + (size_t)(tb + row_) * C_ + (c0_) + sci_ * 8,               \
              lds + (buf) * 40960 + (p * 256 + wave * 64) * 16);              \
    }                                                                         \
    _Pragma("unroll") for (int p = 0; p < 2; p++) {                           \
      int i_ = p * 256 + tid;                                                 \
      int row_ = i_ >> 3;                                                     \
      int sci_ = (i_ & 7) ^ (row_ & 7);                                       \
      gload16(wg + (size_t)(o0 + row_) * C_ + (c0_) + sci_ * 8,               \
              lds + (buf) * 40960 + 32768 + (p * 256 + wave * 64) * 16);      \
    }                                                                         \
  } while (0)

  QSTAGE(0, 0);
  __syncthreads();
  int cur = 0;
  for (int kst = 0; kst < 8; kst++) {
    if (kst < 7) QSTAGE(cur ^ 1, (kst + 1) * 64);  // async prefetch
    const unsigned short* hb = LB + cur * 20480;
    const unsigned short* wb2 = hb + 16384;
    __builtin_amdgcn_s_setprio(1);
#pragma unroll
    for (int ks = 0; ks < 2; ks++) {
      short8 af[4], bfr[4];
#pragma unroll
      for (int mt = 0; mt < 4; mt++)
        af[mt] = *(const short8*)&hb[(w64 + mt * 16 + col) * 64 +
                                     (((ks * 4 + quad) ^ cs) << 3)];
#pragma unroll
      for (int nt = 0; nt < 4; nt++)
        bfr[nt] = *(const short8*)&wb2[(nt * 16 + col) * 64 +
                                       (((ks * 4 + quad) ^ cs) << 3)];
#pragma unroll
      for (int mt = 0; mt < 4; mt++)
#pragma unroll
        for (int nt = 0; nt < 4; nt++)
          acc[mt][nt] = __builtin_amdgcn_mfma_f32_16x16x32_bf16(
              af[mt], bfr[nt], acc[mt][nt], 0, 0, 0);
    }
    __builtin_amdgcn_s_setprio(0);
    __syncthreads();  // drains this wave's prefetch + releases cur buffer
    cur ^= 1;
  }
#undef QSTAGE
  int sec = (o0 >> 6) % 3;
  int hd = o0 / 192;
  const float s = 0.35355339059327373f;       // 64^-0.25
  const float sq = s * 1.4426950408889634f;   // fold log2(e) into q
  if (sec < 2) {
    bf16* dst = (sec == 0) ? qb : kb;
    float sc = (sec == 0) ? sq : s;
    size_t hb2 = (size_t)(bl * NH + hd) * T_ * CH;
    for (int mt = 0; mt < 4; mt++) {
      for (int r = 0; r < 4; r++) {
        int t = tb + w64 + mt * 16 + quad * 4 + r;
        for (int nt = 0; nt < 4; nt++) {
          int ch = nt * 16 + col;
          dst[hb2 + (size_t)t * CH + ch] =
              f2b_fast((acc[mt][nt][r] + qkv_b[o0 + ch]) * sc);
        }
      }
    }
  } else {
    // staging LDS now dead; reuse as St[64][264]
    for (int mt = 0; mt < 4; mt++) {
      for (int r = 0; r < 4; r++) {
        int tl = w64 + mt * 16 + quad * 4 + r;
        for (int nt = 0; nt < 4; nt++) {
          int ch = nt * 16 + col;
          LB[ch * ST_STRIDE + tl] =
              fbits_fast(acc[mt][nt][r] + qkv_b[o0 + ch]);
        }
      }
    }
    __syncthreads();
    int rr = tid >> 2, csx = (tid & 3) * 64;
    size_t base = ((size_t)(bl * NH + hd) * CH + rr) * T_ + tb + csx;
    unsigned short* vg = (unsigned short*)vb;
    for (int j2 = 0; j2 < 8; j2++)
      *(int4*)(vg + base + j2 * 8) =
          *(const int4*)&LB[rr * ST_STRIDE + csx + j2 * 8];
  }
}

// ---------------------------------------------------------------------------
// K5: flash attention v10 = v8 (LDS-staged V — reverting v9's V-in-reg,
// which spilled ~32 VGPRs of V frags to scratch: WRITE_SIZE 16->176 MB,
// 46->150 us) + zero-C MFMA init (first QK MFMA takes z4 as C; deletes 32
// v_mov/tile, no register-pressure change).
// ---------------------------------------------------------------------------
__global__ __launch_bounds__(256, 4) void attn_mfma10(
    const bf16* __restrict__ qb, const bf16* __restrict__ kb,
    const bf16* __restrict__ vb, bf16* __restrict__ a, int nbh) {
  __shared__ __align__(16) unsigned short LB[20480];  // 40960 B
  int bid = blockIdx.x;
  int bh = bid % nbh;           // nbh mult of 8 -> same-head tiles share XCD L2
  int qt0 = (bid / nbh) * 128;
  int tid = threadIdx.x;
  int wave = tid >> 6, lane = tid & 63;
  int col = lane & 15, quad = lane >> 4;
  int cs = col & 7;             // K/V read-side swizzle key
  int ps = (col >> 1) & 3;      // Pst swizzle key (bank-quad spread, 2-way)
  const unsigned short* qg = (const unsigned short*)qb;
  const unsigned short* kg = (const unsigned short*)kb;
  const unsigned short* vg = (const unsigned short*)vb;
  const size_t tmaj = (size_t)bh * T_ * CH;
  const size_t cmaj = (size_t)bh * CH * T_;
  char* lds = (char*)LB;

  int qrow = qt0 + wave * 16 + col;
  short8 bq0[2], bq1[2];
#pragma unroll
  for (int u = 0; u < 2; u++) {
    const unsigned short* qp = qg + tmaj + (size_t)(qrow + u * 64) * CH;
    bq0[u] = *(const short8*)(qp + quad * 8);
    bq1[u] = *(const short8*)(qp + 32 + quad * 8);
  }
  f32x4 Ot0[4], Ot1[4];
#pragma unroll
  for (int mt = 0; mt < 4; mt++) {
    Ot0[mt] = f32x4{0, 0, 0, 0};
    Ot1[mt] = f32x4{0, 0, 0, 0};
  }
  const short ob = (short)0x3F80;  // bf16 1.0
  short8 ones = {ob, ob, ob, ob, ob, ob, ob, ob};
  f32x4 La0 = f32x4{0, 0, 0, 0}, La1 = f32x4{0, 0, 0, 0};
  const f32x4 z4 = {0.f, 0.f, 0.f, 0.f};
  unsigned short* pw0 = LB + 16384 + wave * 512 + col * 32;
  unsigned short* pw1 = pw0 + 2048;

#define STAGE(buf, tt)                                                        \
  do {                                                                        \
    int s0_ = (tt) * 64;                                                      \
    const unsigned short* kt_ = kg + tmaj + (size_t)s0_ * CH;                 \
    const unsigned short* vt_ = vg + cmaj + s0_;                              \
    _Pragma("unroll") for (int cc = 0; cc < 2; cc++) {                        \
      int i_ = cc * 256 + tid;                                                \
      int row_ = i_ >> 3;                                                     \
      int sci_ = (i_ & 7) ^ (row_ & 7);                                       \
      int wb_ = (cc * 256 + wave * 64) * 16; /* wave-uniform LDS base */      \
      gload16(kt_ + (size_t)row_ * CH + sci_ * 8, lds + (buf) * 8192 + wb_);  \
      gload16(vt_ + (size_t)row_ * T_ + sci_ * 8,                             \
              lds + 16384 + (buf) * 8192 + wb_);                              \
    }                                                                         \
  } while (0)

  STAGE(0, 0);
  __syncthreads();
  int cur = 0;
  for (int t = 0; t < 16; t++) {
    if (t < 15) STAGE(cur ^ 1, t + 1);  // async prefetch, no wait
    const char* ksb = lds + cur * 8192;
    const char* vtb = lds + 16384 + cur * 8192;
    // ---- QK^T for both q-halves, K fragments read once, zero-C init ----
    f32x4 St0[4], St1[4];
    __builtin_amdgcn_s_setprio(1);
#pragma unroll
    for (int mt = 0; mt < 4; mt++) {
      int rb = (mt * 16 + col) * 128;
      short8 ak0 = *(const short8*)(ksb + rb + ((quad ^ cs) << 4));
      short8 ak1 = *(const short8*)(ksb + rb + (((quad + 4) ^ cs) << 4));
      St0[mt] = __builtin_amdgcn_mfma_f32_16x16x32_bf16(ak0, bq0[0], z4, 0, 0, 0);
      St1[mt] = __builtin_amdgcn_mfma_f32_16x16x32_bf16(ak0, bq0[1], z4, 0, 0, 0);
      St0[mt] = __builtin_amdgcn_mfma_f32_16x16x32_bf16(ak1, bq1[0], St0[mt], 0, 0, 0);
      St1[mt] = __builtin_amdgcn_mfma_f32_16x16x32_bf16(ak1, bq1[1], St1[mt], 0, 0, 0);
    }
    __builtin_amdgcn_s_setprio(0);
    // ---- softmax (exp2; q carries log2e). l via ones-MFMA below ----
#pragma unroll
    for (int mt = 0; mt < 4; mt++)
#pragma unroll
      for (int r = 0; r < 4; r++) {
        St0[mt][r] = __builtin_amdgcn_exp2f(St0[mt][r]);
        St1[mt][r] = __builtin_amdgcn_exp2f(St1[mt][r]);
      }
    // ---- PV: V fragments read once, shared across both u ----
#pragma unroll
    for (int kc = 0; kc < 2; kc++) {
#pragma unroll
      for (int mh = 0; mh < 2; mh++) {
        int mt = kc * 2 + mh;
        int wsw = (((2 * mh + (quad >> 1)) ^ ps) << 3) + (quad & 1) * 4;
        uint2 k0 = {cvtpk(St0[mt][0], St0[mt][1]),
                    cvtpk(St0[mt][2], St0[mt][3])};
        uint2 k1 = {cvtpk(St1[mt][0], St1[mt][1]),
                    cvtpk(St1[mt][2], St1[mt][3])};
        *(uint2*)(pw0 + wsw) = k0;
        *(uint2*)(pw1 + wsw) = k1;
      }
      int rsw = (quad ^ ps) << 3;
      short8 bp0 = *(const short8*)(pw0 + rsw);
      short8 bp1 = *(const short8*)(pw1 + rsw);
      __builtin_amdgcn_s_setprio(1);
      La0 = __builtin_amdgcn_mfma_f32_16x16x32_bf16(ones, bp0, La0, 0, 0, 0);
      La1 = __builtin_amdgcn_mfma_f32_16x16x32_bf16(ones, bp1, La1, 0, 0, 0);
#pragma unroll
      for (int mt = 0; mt < 4; mt++) {
        short8 av = *(const short8*)(vtb + (mt * 16 + col) * 128 +
                                     (((kc * 4 + quad) ^ cs) << 4));
        Ot0[mt] = __builtin_amdgcn_mfma_f32_16x16x32_bf16(av, bp0, Ot0[mt], 0, 0, 0);
        Ot1[mt] = __builtin_amdgcn_mfma_f32_16x16x32_bf16(av, bp1, Ot1[mt], 0, 0, 0);
      }
      __builtin_amdgcn_s_setprio(0);
    }
    __syncthreads();  // drains this wave's prefetch (vmcnt 0) + syncs buffers
    cur ^= 1;
  }
#undef STAGE
  // epilogue: l = La[0] (every C element of the ones-MFMA holds the full sum)
  int bl = bh >> 3, hd = bh & 7;
  unsigned short* ag = (unsigned short*)a;
#pragma unroll
  for (int u = 0; u < 2; u++) {
    float inv = 1.f / ((u == 0) ? La0[0] : La1[0]);
    const f32x4* Ou = (u == 0) ? Ot0 : Ot1;
    size_t rowb = ((size_t)bl * T_ + qrow + u * 64) * C_ + hd * CH;
#pragma unroll
    for (int mt = 0; mt < 4; mt++) {
      uint2 pk = {cvtpk(Ou[mt][0] * inv, Ou[mt][1] * inv),
                  cvtpk(Ou[mt][2] * inv, Ou[mt][3] * inv)};
      *(uint2*)(ag + rowb + mt * 16 + quad * 4) = pk;
    }
  }
}

// ---------------------------------------------------------------------------
// K6: proj GEMM + residual v4 (unchanged): dbuf prefetch.
// ---------------------------------------------------------------------------
__global__ __launch_bounds__(256) void proj_mfma4(
    const bf16* __restrict__ a, const bf16* __restrict__ wp,
    const float* __restrict__ proj_b, const float* __restrict__ x,
    float* __restrict__ out, int b0) {
  __shared__ __align__(16) unsigned short LB[16384];  // 32768 B (2 bufs)
  int bl = blockIdx.z;
  int b = b0 + bl;
  int o0 = blockIdx.y * 64;
  int t0 = blockIdx.x * 64;
  int tid = threadIdx.x;
  int wave = tid >> 6, lane = tid & 63;
  int col = lane & 15, quad = lane >> 4;
  int cs = col & 7;
  int m0 = wave * 16;
  const unsigned short* ag = (const unsigned short*)a + (size_t)bl * T_ * C_;
  const unsigned short* wg = (const unsigned short*)wp;
  char* lds = (char*)LB;
  f32x4 acc[4] = {f32x4{0,0,0,0}, f32x4{0,0,0,0}, f32x4{0,0,0,0}, f32x4{0,0,0,0}};

#define PSTAGE(buf, c0_)                                                      \
  do {                                                                        \
    _Pragma("unroll") for (int cc = 0; cc < 2; cc++) {                        \
      int i_ = cc * 256 + tid;                                                \
      int row_ = i_ >> 3;                                                     \
      int sci_ = (i_ & 7) ^ (row_ & 7);                                       \
      int wb_ = (cc * 256 + wave * 64) * 16;                                  \
      gload16(ag + (size_t)(t0 + row_) * C_ + (c0_) + sci_ * 8,               \
              lds + (buf) * 16384 + wb_);                                     \
      gload16(wg + (size_t)(o0 + row_) * C_ + (c0_) + sci_ * 8,               \
              lds + (buf) * 16384 + 8192 + wb_);                              \
    }                                                                         \
  } while (0)

  PSTAGE(0, 0);
  __syncthreads();
  int cur = 0;
  for (int kst = 0; kst < 8; kst++) {
    if (kst < 7) PSTAGE(cur ^ 1, (kst + 1) * 64);  // async prefetch
    const unsigned short* ab = LB + cur * 8192;
    const unsigned short* wb2 = ab + 4096;
    __builtin_amdgcn_s_setprio(1);
#pragma unroll
    for (int ks = 0; ks < 2; ks++) {
      short8 aw = *(const short8*)&wb2[(m0 + col) * 64 +
                                       (((ks * 4 + quad) ^ cs) << 3)];
#pragma unroll
      for (int nt = 0; nt < 4; nt++) {
        short8 ba = *(const short8*)&ab[(nt * 16 + col) * 64 +
                                        (((ks * 4 + quad) ^ cs) << 3)];
        acc[nt] = __builtin_amdgcn_mfma_f32_16x16x32_bf16(aw, ba, acc[nt], 0, 0, 0);
      }
    }
    __builtin_amdgcn_s_setprio(0);
    __syncthreads();
    cur ^= 1;
  }
#undef PSTAGE
  for (int r = 0; r < 4; r++) {
    int o = o0 + m0 + quad * 4 + r;
    float bias = proj_b[o];
    size_t rowb = ((size_t)b * C_ + o) * T_ + t0;
    for (int nt = 0; nt < 4; nt++) {
      int t = nt * 16 + col;
      out[rowb + t] = x[rowb + t] + acc[nt][r] + bias;
    }
  }
}

// ---------------------------------------------------------------------------
// Host. Workspace plans (A: all in ws; B: scratch in d_out; C: legacy chunked).
// ---------------------------------------------------------------------------
extern "C" void kernel_launch(void* const* d_in, const int* in_sizes, int n_in,
                              void* d_out, int out_size, void* d_ws,
                              size_t ws_size, hipStream_t stream) {
  const float* x      = (const float*)d_in[0];
  const float* emb    = (const float*)d_in[1];
  const float* gamma  = (const float*)d_in[2];
  const float* beta   = (const float*)d_in[3];
  const float* emb_w  = (const float*)d_in[4];
  const float* emb_b  = (const float*)d_in[5];
  const float* qkv_w  = (const float*)d_in[6];
  const float* qkv_b  = (const float*)d_in[7];
  const float* proj_w = (const float*)d_in[8];
  const float* proj_b = (const float*)d_in[9];
  float* out = (float*)d_out;

  const size_t BUF16 = (size_t)16 * CT * sizeof(bf16);   // 16 MiB per buffer
  const size_t FULL4 = 4 * BUF16;                        // 64 MiB
  const size_t SCR   = 131072 + (size_t)4 * C_ * C_ * sizeof(bf16);

  if (ws_size >= FULL4) {
    // ---- paths A/B: single full-batch pass ----
    bf16* h_buf = (bf16*)d_ws;               // also 'a' after attn
    bf16* q_buf = h_buf + BUF16 / sizeof(bf16);
    bf16* k_buf = q_buf + BUF16 / sizeof(bf16);
    bf16* v_buf = k_buf + BUF16 / sizeof(bf16);
    bool inWs = ws_size >= FULL4 + SCR;
    char* scr = inWs ? ((char*)d_ws + FULL4) : (char*)d_out;
    float* e_buf    = (float*)scr;
    float* mean_buf = e_buf + B_ * 2 * C_;
    float* rstd_buf = mean_buf + B_ * G_;
    bf16*  wq_bf    = (bf16*)(scr + 131072);
    bf16*  wp_bf;
    int nconv;
    if (inWs) {
      wp_bf = wq_bf + (size_t)3 * C_ * C_;
      nconv = 256;            // wq + wp
    } else {
      wp_bf = q_buf;          // filled after attn (q dead by then)
      nconv = 192;            // wq only (192*1024 = 3C^2/4 float4s)
    }
    prep_kernel<<<dim3(nconv + 64 + 512), 1024, 0, stream>>>(
        qkv_w, proj_w, wq_bf, wp_bf, emb, emb_w, emb_b, e_buf, x, mean_buf,
        rstd_buf, nconv);
    norm_film_t2<<<dim3(16, 8, 16), 256, 0, stream>>>(
        x, mean_buf, rstd_buf, gamma, beta, e_buf, h_buf, 0);
    qkv_gemm_mfma5<<<dim3(24 * 64), 256, 0, stream>>>(h_buf, wq_bf, qkv_b,
                                                      q_buf, k_buf, v_buf, 64);
    attn_mfma10<<<dim3(8 * 128), 256, 0, stream>>>(q_buf, k_buf, v_buf, h_buf,
                                                   128);
    if (!inWs)
      convert_one<<<dim3(256), 256, 0, stream>>>(proj_w, wp_bf);
    proj_mfma4<<<dim3(16, 8, 16), 256, 0, stream>>>(h_buf, wp_bf, proj_b, x,
                                                    out, 0);
  } else {
    // ---- path C: legacy chunked layout ----
    float* e_buf    = (float*)d_ws;
    float* mean_buf = e_buf + B_ * 2 * C_;
    float* rstd_buf = mean_buf + B_ * G_;
    bf16*  wq_bf    = (bf16*)((char*)d_ws + 131072);
    bf16*  wp_bf    = wq_bf + (size_t)3 * C_ * C_;
    bf16* pool = (bf16*)((char*)d_ws + SCR);
    size_t avail = ws_size > SCR ? ws_size - SCR : 0;
    int NB = 16;
    while (NB > 1 && (size_t)4 * NB * CT * sizeof(bf16) > avail) NB >>= 1;
    bf16* h_buf = pool;
    bf16* q_buf = h_buf + (size_t)NB * CT;
    bf16* k_buf = q_buf + (size_t)NB * CT;
    bf16* v_buf = k_buf + (size_t)NB * CT;

    prep_kernel<<<dim3(256 + 64 + 512), 1024, 0, stream>>>(
        qkv_w, proj_w, wq_bf, wp_bf, emb, emb_w, emb_b, e_buf, x, mean_buf,
        rstd_buf, 256);
    for (int b0 = 0; b0 < B_; b0 += NB) {
      norm_film_t2<<<dim3(16, 8, NB), 256, 0, stream>>>(
          x, mean_buf, rstd_buf, gamma, beta, e_buf, h_buf, b0);
      qkv_gemm_mfma5<<<dim3(24 * 4 * NB), 256, 0, stream>>>(
          h_buf, wq_bf, qkv_b, q_buf, k_buf, v_buf, 4 * NB);
      int nbh = NB * NH;
      attn_mfma10<<<dim3(8 * nbh), 256, 0, stream>>>(q_buf, k_buf, v_buf,
                                                     h_buf, nbh);
      proj_mfma4<<<dim3(16, 8, NB), 256, 0, stream>>>(h_buf, wp_bf, proj_b, x,
                                                      out, b0);
    }
  }
}